// Round 15
// baseline (294.020 us; speedup 1.0000x reference)
//
#include <hip/hip_runtime.h>
#include <math.h>

// GCN 2-layer: N=100K nodes, E=3.2M edges (+N self loops), 64 -> 128 -> 64.
//  - Fold norm: out[d] = dinv[d] * sum_s (dinv[s]*h[s]) + b
//  - R22 verified optimum: 278.9us = build(512,staged)~40 + finalize~25 +
//    agg1 53.5 + mlp(reg-weights) ~13 + agg2 53.5 + ~90us dispatch overhead.
//  - Gather variants measured: R16 idiom BEST (53.5); R17 clamp-free -13%;
//    R15 nt+voffset -8%; R21 chunk-major -130%. Keep R16-exact.
//  - R19: many-block scatter fragments write slices (WRITE_SIZE 2x).
//  - R23/R24: re-fuse agg1+mlp WITH the R20 weight hoist. R11's 79.4us
//    fused kernel was 53.5 agg + ~24 WEIGHT RELOAD (same disease R20 cured
//    in standalone mlp) -- not imbalance. Fused+hoisted: persistent 2048
//    blocks, weights in 32 VGPR once/block, per-16-row tile: gather ->
//    sA1[16][72] -> GEMM1 -> sH[16][136] -> GEMM2 -> h2s. Kills A1
//    buffer (25MB) + one dispatch/gap. (R23 bench was an infra failure --
//    container acquisition -- kernel never ran; this is a resubmit.)

#define IN_C 64
#define HID_C 128
#define OUT_C 64
#define BSHIFT 9
#define BW (1 << BSHIFT)          // 512 nodes per bucket
#define NPB 512                   // build partition blocks
#define CAP 24576                 // per-bucket ebuf region capacity
#define CH_MAX 6272               // LDS edge-stage capacity (chunk = 6250)

typedef __attribute__((ext_vector_type(8))) short bf16x8;
typedef __attribute__((ext_vector_type(4))) float f32x4;
typedef __attribute__((ext_vector_type(2))) float v2f;

__device__ __forceinline__ unsigned short f2bf(float f) {
  unsigned u = __float_as_uint(f);
  return (unsigned short)((u + 0x7FFF + ((u >> 16) & 1)) >> 16);  // RNE
}
__device__ __forceinline__ v2f cvt2(unsigned u) {
  v2f r;
  r.x = __uint_as_float(u << 16);          // low bf16 -> f32
  r.y = __uint_as_float(u & 0xFFFF0000u);  // high bf16 -> f32
  return r;
}
__device__ __forceinline__ unsigned pack2(v2f v) {
  return ((unsigned)f2bf(v.y) << 16) | f2bf(v.x);
}

// ---- fused CSR build: detect + LDS stage + hist + claim + scatter ----------
// R16-exact staged form, 512 blocks x 256 threads. grid = NPB + 33.

__global__ __launch_bounds__(256) void k_build(const int* __restrict__ ei, int e, int n,
    int nb, int* __restrict__ gcnt, unsigned* __restrict__ ebuf,
    const float* __restrict__ W1, const float* __restrict__ W2,
    unsigned short* __restrict__ Wt1, unsigned short* __restrict__ Wt2,
    unsigned short* __restrict__ xs_zero, unsigned short* __restrict__ h2s_zero) {
  const int t = threadIdx.x;
  if (blockIdx.x >= NPB) {                 // extra blocks: weights + zero rows
    int bb = blockIdx.x - NPB;
    if (bb == 32) {
      if (t < 64) { xs_zero[t] = 0; h2s_zero[t] = 0; }
      return;
    }
    int i = bb * 256 + t;
    if (i < IN_C * HID_C) {
      int k = i >> 7, c = i & (HID_C - 1);
      Wt1[c * IN_C + k] = f2bf(W1[i]);
    }
    if (i < HID_C * OUT_C) {
      int k = i >> 6, c = i & (OUT_C - 1);
      Wt2[c * HID_C + k] = f2bf(W2[i]);
    }
    return;
  }
  __shared__ unsigned lpay[CH_MAX];
  __shared__ unsigned char lbuck[CH_MAX];
  __shared__ int lh[256];
  __shared__ int lbase[256];
  __shared__ int lcur[256];
  __shared__ int sflag;
  if (t == 0) sflag = 0;
  __syncthreads();
  const int chunk = (e + NPB - 1) / NPB;
  const int lo = blockIdx.x * chunk;
  const int hi = min(lo + chunk, e);
  {  // per-chunk int32/int64 detect: odd words of int64 values (<2^31) are 0
    int lim = min(hi, lo + 512);
    int f = 0;
    for (int i = lo + t; i < lim; i += 256)
      if (ei[2 * i + 1] != 0) f = 1;
    if (f) sflag = 1;
  }
  __syncthreads();
  const int f = sflag;                     // 1 => int32 layout
  for (int sub = lo; sub < hi; sub += CH_MAX) {
    const int shi = min(sub + CH_MAX, hi);
    const int mm = shi - sub;
    for (int i = t; i < nb; i += 256) lh[i] = 0;
    __syncthreads();
    for (int i = sub + t; i < shi; i += 256) {
      int s, d;
      if (f) {
        s = __builtin_nontemporal_load(&ei[i]);
        d = __builtin_nontemporal_load(&ei[e + i]);
      } else {
        s = (int)__builtin_nontemporal_load(&((const long long*)ei)[i]);
        d = (int)__builtin_nontemporal_load(&((const long long*)ei)[e + i]);
      }
      s = min(max(s, 0), n - 1);
      d = min(max(d, 0), n - 1);
      int bk = d >> BSHIFT;
      lpay[i - sub] = ((unsigned)(d & (BW - 1)) << 23) | (unsigned)s;
      lbuck[i - sub] = (unsigned char)bk;
      atomicAdd(&lh[bk], 1);
    }
    __syncthreads();
    for (int i = t; i < nb; i += 256) {
      int c = lh[i];
      lbase[i] = c ? atomicAdd(&gcnt[i], c) : 0;  // claim region slice
      lcur[i] = 0;
    }
    __syncthreads();
    for (int i = t; i < mm; i += 256) {
      int bk = lbuck[i];
      int slot = lbase[bk] + atomicAdd(&lcur[bk], 1);
      if (slot < CAP) ebuf[(size_t)bk * CAP + slot] = lpay[i];
      // slot >= CAP statistically impossible for this input; dropped entries
      // keep memory safety (finalize clamps counts).
    }
    __syncthreads();
  }
}

// ---- per-bucket finalize: degree, scan, row_ptr, dinv, col scatter, xs -----
// 1024 threads (16 waves) for latency hiding; scans guarded to t<256.

__global__ __launch_bounds__(1024) void k_finalize(const unsigned* __restrict__ ebuf,
    const int* __restrict__ gcnt, const float* __restrict__ x,
    unsigned short* __restrict__ xs, int n, int nb,
    int* __restrict__ row_ptr, float* __restrict__ dinv, int* __restrict__ col) {
  __shared__ int sc[256];
  __shared__ int ldeg[BW];
  __shared__ int lofs[BW];
  __shared__ int lcur[BW];
  __shared__ float sdv[BW];
  __shared__ int wsum[256];
  const int b = blockIdx.x;
  const int t = threadIdx.x;
  const int T = 1024;
  int cnt = 0, nodes = 0;
  if (t < nb) {
    cnt = min(gcnt[t], CAP);
    nodes = min(BW, n - t * BW);
  }
  if (t < 256) sc[t] = cnt + nodes;
  __syncthreads();
  for (int off = 1; off < 256; off <<= 1) {
    int vc = 0;
    if (t < 256 && t >= off) vc = sc[t - off];
    __syncthreads();
    if (t < 256) sc[t] += vc;
    __syncthreads();
  }
  const int cntb = min(gcnt[b], CAP);
  const int eb = b * CAP;
  const int ee = eb + cntb;
  const int cb = (b == 0) ? 0 : sc[b - 1];
  const int lo = b * BW;
  const int nn = min(BW, n - lo);
  for (int k = t; k < BW; k += T) ldeg[k] = 0;
  __syncthreads();
  for (int k = t; k < nn; k += T) ldeg[k] = 1;  // self-loop
  __syncthreads();
  for (int j = eb + t; j < ee; j += T) {
    int dl = (int)(ebuf[j] >> 23);
    atomicAdd(&ldeg[dl], 1);
  }
  __syncthreads();
  int p0 = 0, p1 = 0;
  if (t < 256) {
    p0 = ldeg[2 * t]; p1 = ldeg[2 * t + 1];
    wsum[t] = p0 + p1;
  }
  __syncthreads();
  for (int off = 1; off < 256; off <<= 1) {
    int v = 0;
    if (t < 256 && t >= off) v = wsum[t - off];
    __syncthreads();
    if (t < 256) wsum[t] += v;
    __syncthreads();
  }
  if (t < 256) {
    int pb = (t == 0) ? 0 : wsum[t - 1];
    lofs[2 * t] = pb;
    lofs[2 * t + 1] = pb + p0;
  }
  __syncthreads();
  for (int k = t; k < nn; k += T) {
    int base = cb + lofs[k];
    float dv = rsqrtf((float)ldeg[k]);
    row_ptr[lo + k] = base;
    dinv[lo + k] = dv;
    sdv[k] = dv;
    col[base] = lo + k;          // self-loop entry
    lcur[k] = lofs[k] + 1;
  }
  if (b == nb - 1 && t == 0) row_ptr[n] = sc[nb - 1];
  __syncthreads();
  for (int j = eb + t; j < ee; j += T) {
    unsigned pk = ebuf[j];
    int s = (int)(pk & 0x7FFFFF);
    int dl = (int)(pk >> 23);
    int p = atomicAdd(&lcur[dl], 1);
    col[cb + p] = s;
  }
  // fused k_scale: xs[row] = bf16(x[row] * dinv[row]) for this bucket's rows
  const float4* x4 = (const float4*)x;
  for (int idx = t; idx < nn * 16; idx += T) {
    int row = idx >> 4, q = idx & 15;
    float sc2 = sdv[row];
    float4 v = x4[(size_t)(lo + row) * 16 + q];
    ushort4 o;
    o.x = f2bf(v.x * sc2); o.y = f2bf(v.y * sc2);
    o.z = f2bf(v.z * sc2); o.w = f2bf(v.w * sc2);
    ((ushort4*)xs)[(size_t)(lo + row) * 16 + q] = o;
  }
}

// ---- fused layer-1 agg + MLP, persistent grid-stride, reg-hoisted weights -
// Per 16-row tile: Phase A = R16-EXACT gather (4 rows/wave; clamped
// zero-row loads are L1 hits buying latency hiding -- R17 lesson) into
// sA1[16][72]; Phase B: GEMM1(+bias,relu,*dinv) -> sH[16][136]; GEMM2 ->
// h2s. Weights live in 32 VGPR/lane, loaded ONCE per block (R20 lesson --
// R11's fused 79.4us was 53.5 agg + 24us weight reloads, not imbalance).

__global__ __launch_bounds__(256) void k_aggmlp(const unsigned short* __restrict__ feat,
    const int* __restrict__ row_ptr, const int* __restrict__ col,
    const float* __restrict__ dinv, const unsigned short* __restrict__ Wt1,
    const unsigned short* __restrict__ Wt2, const float* __restrict__ b1,
    unsigned short* __restrict__ h2s, int n) {
  __shared__ __align__(16) unsigned short sA1[16][72];
  __shared__ __align__(16) unsigned short sH[16][136];
  const int wv = threadIdx.x >> 6;
  const int lane = threadIdx.x & 63;
  const int es = lane >> 3;      // edge slot 0..7
  const int c8 = lane & 7;       // 16B channel chunk (8 ch)
  const int m = lane & 15;
  const int q = lane >> 4;
  const uint4* f16 = (const uint4*)feat;   // row stride = 8 chunks
  // weight fragments in registers, loaded once per block
  bf16x8 w1a[2], w1b[2], w2[4];
#pragma unroll
  for (int kt = 0; kt < 2; kt++) {
    w1a[kt] = *(const bf16x8*)&Wt1[(size_t)(wv * 16 + m) * IN_C + kt * 32 + q * 8];
    w1b[kt] = *(const bf16x8*)&Wt1[(size_t)((wv + 4) * 16 + m) * IN_C + kt * 32 + q * 8];
  }
#pragma unroll
  for (int kt = 0; kt < 4; kt++)
    w2[kt] = *(const bf16x8*)&Wt2[(size_t)(wv * 16 + m) * HID_C + kt * 32 + q * 8];
  const float bv0 = b1[wv * 16 + m];
  const float bv1 = b1[(wv + 4) * 16 + m];
  const int ntiles = (n + 15) >> 4;
  for (int tile = blockIdx.x; tile < ntiles; tile += gridDim.x) {
    const int r0 = tile * 16;
    // ---- Phase A: wave wv aggregates rows r0+wv*4..+3 (R16-exact body)
    for (int rr = 0; rr < 4; ++rr) {
      const int d = r0 + wv * 4 + rr;
      if (d < n) {
        const int beg = row_ptr[d], end = row_ptr[d + 1];
        const int rem = end - beg - es;
        const int c = (rem > 0) ? ((rem + 7) >> 3) : 0;
        const int last = end - 1;
        v2f a0 = {0.f, 0.f}, a1 = {0.f, 0.f}, a2 = {0.f, 0.f}, a3 = {0.f, 0.f};
        for (int g = 0; g < c; g += 4) {
          int j0 = beg + es + 8 * g;
          int i0 = col[j0];
          int i1 = col[min(j0 + 8, last)];
          int i2 = col[min(j0 + 16, last)];
          int i3 = col[min(j0 + 24, last)];
          if (g + 1 >= c) i1 = n;
          if (g + 2 >= c) i2 = n;
          if (g + 3 >= c) i3 = n;
          uint4 u0 = f16[(size_t)i0 * 8 + c8];
          uint4 u1 = f16[(size_t)i1 * 8 + c8];
          uint4 u2 = f16[(size_t)i2 * 8 + c8];
          uint4 u3 = f16[(size_t)i3 * 8 + c8];
          a0 += cvt2(u0.x) + cvt2(u1.x) + cvt2(u2.x) + cvt2(u3.x);
          a1 += cvt2(u0.y) + cvt2(u1.y) + cvt2(u2.y) + cvt2(u3.y);
          a2 += cvt2(u0.z) + cvt2(u1.z) + cvt2(u2.z) + cvt2(u3.z);
          a3 += cvt2(u0.w) + cvt2(u1.w) + cvt2(u2.w) + cvt2(u3.w);
        }
#pragma unroll
        for (int off = 8; off <= 32; off <<= 1) {
          v2f o0, o1, o2, o3;
          o0.x = __shfl_xor(a0.x, off); o0.y = __shfl_xor(a0.y, off);
          o1.x = __shfl_xor(a1.x, off); o1.y = __shfl_xor(a1.y, off);
          o2.x = __shfl_xor(a2.x, off); o2.y = __shfl_xor(a2.y, off);
          o3.x = __shfl_xor(a3.x, off); o3.y = __shfl_xor(a3.y, off);
          a0 += o0; a1 += o1; a2 += o2; a3 += o3;
        }
        if (es == 0) {
          float sc = dinv[d];
          v2f vs = {sc, sc};
          a0 *= vs; a1 *= vs; a2 *= vs; a3 *= vs;
          uint4 o;
          o.x = pack2(a0); o.y = pack2(a1); o.z = pack2(a2); o.w = pack2(a3);
          *(uint4*)&sA1[wv * 4 + rr][c8 * 8] = o;
        }
      } else if (es == 0) {
        uint4 z = {0u, 0u, 0u, 0u};
        *(uint4*)&sA1[wv * 4 + rr][c8 * 8] = z;
      }
    }
    __syncthreads();
    // ---- Phase B1: GEMM1 C1[16][128]; wave wv covers col-tiles wv, wv+4
    f32x4 acc0 = {0.f, 0.f, 0.f, 0.f}, acc1 = {0.f, 0.f, 0.f, 0.f};
#pragma unroll
    for (int kt = 0; kt < 2; kt++) {
      bf16x8 a = *(const bf16x8*)&sA1[m][kt * 32 + q * 8];
      acc0 = __builtin_amdgcn_mfma_f32_16x16x32_bf16(a, w1a[kt], acc0, 0, 0, 0);
      acc1 = __builtin_amdgcn_mfma_f32_16x16x32_bf16(a, w1b[kt], acc1, 0, 0, 0);
    }
    float dv[4];
#pragma unroll
    for (int i = 0; i < 4; i++) dv[i] = dinv[min(r0 + q * 4 + i, n - 1)];
    {
      int c = wv * 16 + m;
#pragma unroll
      for (int i = 0; i < 4; i++)
        sH[q * 4 + i][c] = f2bf(fmaxf(acc0[i] + bv0, 0.f) * dv[i]);
      c = (wv + 4) * 16 + m;
#pragma unroll
      for (int i = 0; i < 4; i++)
        sH[q * 4 + i][c] = f2bf(fmaxf(acc1[i] + bv1, 0.f) * dv[i]);
    }
    __syncthreads();
    // ---- Phase B2: GEMM2 C2[16][64]; wave wv covers cols wv*16..+15
    f32x4 acc = {0.f, 0.f, 0.f, 0.f};
#pragma unroll
    for (int kt = 0; kt < 4; kt++) {
      bf16x8 a = *(const bf16x8*)&sH[m][kt * 32 + q * 8];
      acc = __builtin_amdgcn_mfma_f32_16x16x32_bf16(a, w2[kt], acc, 0, 0, 0);
    }
    int c = wv * 16 + m;
#pragma unroll
    for (int i = 0; i < 4; i++) {
      int row = r0 + q * 4 + i;
      if (row < n) h2s[(size_t)row * OUT_C + c] = f2bf(acc[i]);
    }
    __syncthreads();   // sA1/sH reused next tile
  }
}

// ---- layer-2 aggregation: R16-EXACT gather (h2s, bias, f32 out) ------------

__global__ __launch_bounds__(256) void k_agg2(const unsigned short* __restrict__ feat,
    const int* __restrict__ row_ptr, const int* __restrict__ col,
    const float* __restrict__ dinv, const float* __restrict__ bias,
    float* __restrict__ out, int n) {
  const int wid = threadIdx.x >> 6;
  const int lane = threadIdx.x & 63;
  const int es = lane >> 3;      // edge slot 0..7
  const int c8 = lane & 7;       // 16B channel chunk (8 ch)
  const int d = blockIdx.x * 4 + wid;
  if (d >= n) return;
  const int beg = row_ptr[d], end = row_ptr[d + 1];
  const uint4* f16 = (const uint4*)feat;   // row stride = 8 chunks
  const int rem = end - beg - es;
  const int c = (rem > 0) ? ((rem + 7) >> 3) : 0;
  const int last = end - 1;
  v2f a0 = {0.f, 0.f}, a1 = {0.f, 0.f}, a2 = {0.f, 0.f}, a3 = {0.f, 0.f};
  for (int g = 0; g < c; g += 4) {
    int j0 = beg + es + 8 * g;
    int i0 = col[j0];
    int i1 = col[min(j0 + 8, last)];
    int i2 = col[min(j0 + 16, last)];
    int i3 = col[min(j0 + 24, last)];
    if (g + 1 >= c) i1 = n;
    if (g + 2 >= c) i2 = n;
    if (g + 3 >= c) i3 = n;
    uint4 u0 = f16[(size_t)i0 * 8 + c8];
    uint4 u1 = f16[(size_t)i1 * 8 + c8];
    uint4 u2 = f16[(size_t)i2 * 8 + c8];
    uint4 u3 = f16[(size_t)i3 * 8 + c8];
    a0 += cvt2(u0.x) + cvt2(u1.x) + cvt2(u2.x) + cvt2(u3.x);
    a1 += cvt2(u0.y) + cvt2(u1.y) + cvt2(u2.y) + cvt2(u3.y);
    a2 += cvt2(u0.z) + cvt2(u1.z) + cvt2(u2.z) + cvt2(u3.z);
    a3 += cvt2(u0.w) + cvt2(u1.w) + cvt2(u2.w) + cvt2(u3.w);
  }
#pragma unroll
  for (int off = 8; off <= 32; off <<= 1) {
    v2f o0, o1, o2, o3;
    o0.x = __shfl_xor(a0.x, off); o0.y = __shfl_xor(a0.y, off);
    o1.x = __shfl_xor(a1.x, off); o1.y = __shfl_xor(a1.y, off);
    o2.x = __shfl_xor(a2.x, off); o2.y = __shfl_xor(a2.y, off);
    o3.x = __shfl_xor(a3.x, off); o3.y = __shfl_xor(a3.y, off);
    a0 += o0; a1 += o1; a2 += o2; a3 += o3;
  }
  if (es == 0) {
    float sc = dinv[d];
    v2f vs = {sc, sc};
    a0 *= vs; a1 *= vs; a2 *= vs; a3 *= vs;
    const v2f* b2v = (const v2f*)bias;
    a0 += b2v[c8 * 4 + 0]; a1 += b2v[c8 * 4 + 1];
    a2 += b2v[c8 * 4 + 2]; a3 += b2v[c8 * 4 + 3];
    float4* o4 = (float4*)out;
    o4[(size_t)d * 16 + c8 * 2]     = make_float4(a0.x, a0.y, a1.x, a1.y);
    o4[(size_t)d * 16 + c8 * 2 + 1] = make_float4(a2.x, a2.y, a3.x, a3.y);
  }
}

// ---- launch ---------------------------------------------------------------

extern "C" void kernel_launch(void* const* d_in, const int* in_sizes, int n_in,
                              void* d_out, int out_size, void* d_ws, size_t ws_size,
                              hipStream_t stream) {
  const float* x  = (const float*)d_in[0];
  const int*   ei = (const int*)d_in[1];
  const float* W1 = (const float*)d_in[2];
  const float* b1 = (const float*)d_in[3];
  const float* W2 = (const float*)d_in[4];
  const float* b2 = (const float*)d_in[5];
  float* out = (float*)d_out;

  const int n = in_sizes[0] / IN_C;   // 100000
  const int e = in_sizes[1] / 2;      // 3200000
  const int nb = (n + BW - 1) >> BSHIFT;  // 196 (must be <= 256)

  char* p = (char*)d_ws;
  auto alloc = [&](size_t bytes) {
    char* r = p;
    p += (bytes + 255) & ~(size_t)255;
    return r;
  };
  int*   gcnt       = (int*)alloc((size_t)nb * 4);
  int*   row_ptr    = (int*)alloc((size_t)(n + 1) * 4);
  float* dinv       = (float*)alloc((size_t)n * 4);
  int*   col        = (int*)alloc((size_t)(e + n) * 4);
  unsigned* ebuf    = (unsigned*)alloc((size_t)nb * CAP * 4);
  unsigned short* xs  = (unsigned short*)alloc((size_t)(n + 1) * IN_C * 2);   // + zero row
  unsigned short* h2s = (unsigned short*)alloc((size_t)(n + 1) * OUT_C * 2);  // + zero row
  unsigned short* Wt1 = (unsigned short*)alloc((size_t)IN_C * HID_C * 2);
  unsigned short* Wt2 = (unsigned short*)alloc((size_t)HID_C * OUT_C * 2);

  hipMemsetAsync(gcnt, 0, (size_t)nb * 4, stream);

  // Fused CSR build (+ weight conversion + zero rows in extra blocks)
  k_build<<<NPB + 33, 256, 0, stream>>>(ei, e, n, nb, gcnt, ebuf, W1, W2, Wt1, Wt2,
      xs + (size_t)n * IN_C, h2s + (size_t)n * OUT_C);
  k_finalize<<<nb, 1024, 0, stream>>>(ebuf, gcnt, x, xs, n, nb, row_ptr, dinv, col);

  // Fused layer-1 aggregate + MLP -> bf16 h2s; layer 2 aggregate -> out
  k_aggmlp<<<2048, 256, 0, stream>>>(xs, row_ptr, col, dinv, Wt1, Wt2, b1, h2s, n);
  k_agg2<<<(n + 3) / 4, 256, 0, stream>>>(h2s, row_ptr, col, dinv, b2, out, n);
}